// Round 10
// baseline (158.731 us; speedup 1.0000x reference)
//
#include <hip/hip_runtime.h>

using short8  = __attribute__((ext_vector_type(8))) short;
using ushort8 = __attribute__((ext_vector_type(8))) unsigned short;
using f32x4   = __attribute__((ext_vector_type(4))) float;

constexpr int   N = 8192;
constexpr int   D = 512;
constexpr float INV_T_LOG2E = 2.8853900817779268f;  // (1/0.5) * log2(e)
constexpr int   CGROUPS = 32;                        // 32 col groups of 256

static __device__ __forceinline__ unsigned short f2bf(float x) {
  unsigned u = __float_as_uint(x);
  unsigned r = (u + 0x7fffu + ((u >> 16) & 1u)) >> 16;   // RNE
  return (unsigned short)r;
}

static __device__ __forceinline__ void gld16(const unsigned short* g, unsigned short* l) {
  __builtin_amdgcn_global_load_lds(
      (const __attribute__((address_space(1))) void*)g,
      (__attribute__((address_space(3))) void*)l, 16, 0, 0);
}

// One wave per row; rows [0,N) -> out0, [N,2N) -> out1.
__global__ __launch_bounds__(256) void normalize_kernel(
    const float* __restrict__ in0, const float* __restrict__ in1,
    unsigned short* __restrict__ n0, unsigned short* __restrict__ n1) {
  int gw   = (blockIdx.x * 256 + threadIdx.x) >> 6;
  int lane = threadIdx.x & 63;
  const float* src = (gw < N) ? in0 + (size_t)gw * D : in1 + (size_t)(gw - N) * D;
  unsigned short* dst = (gw < N) ? n0 + (size_t)gw * D : n1 + (size_t)(gw - N) * D;

  const float4* s4 = reinterpret_cast<const float4*>(src) + (size_t)lane * 2;
  float4 v0 = s4[0], v1 = s4[1];
  float ss = v0.x*v0.x + v0.y*v0.y + v0.z*v0.z + v0.w*v0.w
           + v1.x*v1.x + v1.y*v1.y + v1.z*v1.z + v1.w*v1.w;
#pragma unroll
  for (int m = 1; m <= 32; m <<= 1) ss += __shfl_xor(ss, m);
  float scale = 1.0f / fmaxf(sqrtf(ss), 1e-12f);

  ushort8 o;
  o[0] = f2bf(v0.x * scale); o[1] = f2bf(v0.y * scale);
  o[2] = f2bf(v0.z * scale); o[3] = f2bf(v0.w * scale);
  o[4] = f2bf(v1.x * scale); o[5] = f2bf(v1.y * scale);
  o[6] = f2bf(v1.z * scale); o[7] = f2bf(v1.w * scale);
  *(reinterpret_cast<ushort8*>(dst) + lane) = o;
}

// Persistent fused GEMM: 256 blocks (1/CU), each block = 1 rowtile x 4 colgroups,
// ONE continuous 64-K-tile pipeline (4-deep circular LDS, counted vmcnt gates).
// Epilogue is per-m folded (low register pressure; no spill) and uses
// lgkm-only barriers so staging never drains.
__global__ __launch_bounds__(512, 2) void ntxent_main(
    const unsigned short* __restrict__ n0, const unsigned short* __restrict__ n1,
    const int* __restrict__ labels,
    float* __restrict__ part_pos, float* __restrict__ part_all) {
  __shared__ unsigned short As[4][256 * 32];   // 64 KiB
  __shared__ unsigned short Bs[4][256 * 32];   // 64 KiB
  __shared__ float redS[2048];                 // 8 KiB: [8][128] all + [8][128] pos

  const int t    = threadIdx.x;
  const int lane = t & 63;
  const int wid  = t >> 6;
  const int lr   = lane & 15;
  const int lhi  = lane >> 4;
  const int wr   = wid >> 2;   // 0/1 : rows wr*128..+128
  const int wc   = wid & 3;    // 0..3: cols wc*64..+64

  const int xcd     = blockIdx.x & 7;    // natural XCD assignment (bid % 8)
  const int rowtile = blockIdx.x >> 3;   // 0..31
  const int rowbase = rowtile * 256;

  // ---- staging addresses (pre-swizzled global source; linear gld16 dest) ----
  const int gslot = (t & 3) ^ ((t >> 3) & 3);
  const unsigned short* gA = n0 + (size_t)(rowbase + (t >> 2)) * D + gslot * 8;

  // ---- ds_read indices (swizzled; measured 0-conflict) ----
  const int ksl = lhi ^ ((lr >> 1) & 3);
  int aidx[8];
#pragma unroll
  for (int m = 0; m < 8; ++m) aidx[m] = (wr * 128 + m * 16 + lr) * 32 + ksl * 8;
  int bidx[4];
#pragma unroll
  for (int j = 0; j < 4; ++j) bidx[j] = (wc * 64 + j * 16 + lr) * 32 + ksl * 8;

#define GATE8 asm volatile("s_waitcnt vmcnt(8)\n\ts_barrier" ::: "memory")
#define GATE4 asm volatile("s_waitcnt vmcnt(4)\n\ts_barrier" ::: "memory")
#define GATE0 asm volatile("s_waitcnt vmcnt(0)\n\ts_barrier" ::: "memory")
#define EBAR  asm volatile("s_waitcnt lgkmcnt(0)\n\ts_barrier" ::: "memory")

  // row labels (fixed for the whole block)
  int labr[8][4];
#pragma unroll
  for (int m = 0; m < 8; ++m)
#pragma unroll
    for (int r = 0; r < 4; ++r)
      labr[m][r] = labels[rowbase + wr * 128 + m * 16 + lhi * 4 + r];

  f32x4 acc[8][4];
#pragma unroll
  for (int m = 0; m < 8; ++m)
#pragma unroll
    for (int j = 0; j < 4; ++j) acc[m][j] = (f32x4){0.f, 0.f, 0.f, 0.f};

  // prologue: stage global k-tiles 0,1,2 (tile tt=0)
  {
    const unsigned short* gB0 =
        n1 + (size_t)((xcd * 4) * 256 + (t >> 2)) * D + gslot * 8;
#pragma unroll
    for (int pt = 0; pt < 3; ++pt) {
      const unsigned short* ga = gA + pt * 32;
      const unsigned short* gb = gB0 + pt * 32;
      unsigned short* la = &As[pt][0] + wid * 512;
      unsigned short* lb = &Bs[pt][0] + wid * 512;
      gld16(ga, la); gld16(ga + (size_t)128 * D, la + 4096);
      gld16(gb, lb); gld16(gb + (size_t)128 * D, lb + 4096);
    }
  }

  for (int tt = 0; tt < 4; ++tt) {
    const int cg   = xcd * 4 + tt;
    const int colb = cg * 256;
    const unsigned short* gBc = n1 + (size_t)(colb + (t >> 2)) * D + gslot * 8;
    const unsigned short* gBn = gBc + (size_t)256 * D;   // next tile (unused at tt=3)
    const bool last = (tt == 3);

#pragma unroll
    for (int kk = 0; kk < 16; ++kk) {
      // gate: drain own oldest k-tile's 4 loads, keep 8 in flight
      if (last && kk == 15)      { GATE0; }
      else if (last && kk == 14) { GATE4; }
      else                       { GATE8; }

      // stage global k-tile kk+3 into buf (kk+3)&3 (readers finished, see gate)
      if (!(last && kk >= 13)) {
        const int sb = (kk + 3) & 3;
        const unsigned short* ga = gA + ((kk + 3) & 15) * 32;
        const unsigned short* gb =
            (kk < 13) ? (gBc + (kk + 3) * 32) : (gBn + (kk - 13) * 32);
        unsigned short* la = &As[sb][0] + wid * 512;
        unsigned short* lb = &Bs[sb][0] + wid * 512;
        gld16(ga, la); gld16(ga + (size_t)128 * D, la + 4096);
        gld16(gb, lb); gld16(gb + (size_t)128 * D, lb + 4096);
      }

      // compute on buf kk&3
      const unsigned short* bufA = &As[kk & 3][0];
      const unsigned short* bufB = &Bs[kk & 3][0];
      short8 a[8], b[4];
#pragma unroll
      for (int m = 0; m < 8; ++m) a[m] = *(const short8*)&bufA[aidx[m]];
#pragma unroll
      for (int j = 0; j < 4; ++j) b[j] = *(const short8*)&bufB[bidx[j]];

      __builtin_amdgcn_s_setprio(1);
#pragma unroll
      for (int m = 0; m < 8; ++m)
#pragma unroll
        for (int j = 0; j < 4; ++j)
          acc[m][j] = __builtin_amdgcn_mfma_f32_16x16x32_bf16(a[m], b[j], acc[m][j], 0, 0, 0);
      __builtin_amdgcn_s_setprio(0);
    }

    // ---- per-tile epilogue, per-m folded (low pressure; lgkm barriers only) ----
    int labc[4];
#pragma unroll
    for (int j = 0; j < 4; ++j) labc[j] = labels[colb + wc * 64 + j * 16 + lr];

    float* redSa = redS;            // [8][128]
    float* redSp = redS + 1024;     // [8][128]
#pragma unroll
    for (int m = 0; m < 8; ++m) {
      float asum[4] = {0.f, 0.f, 0.f, 0.f};
      float psum[4] = {0.f, 0.f, 0.f, 0.f};
#pragma unroll
      for (int j = 0; j < 4; ++j)
#pragma unroll
        for (int r = 0; r < 4; ++r) {
          float e = exp2f(acc[m][j][r] * INV_T_LOG2E);
          asum[r] += e;
          if (labr[m][r] == labc[j]) psum[r] += e;
        }
#pragma unroll
      for (int msk = 1; msk <= 8; msk <<= 1)
#pragma unroll
        for (int r = 0; r < 4; ++r) {
          asum[r] += __shfl_xor(asum[r], msk);
          psum[r] += __shfl_xor(psum[r], msk);
        }
      if (lr == 0) {
#pragma unroll
        for (int r = 0; r < 4; ++r) {
          redSa[wid * 128 + m * 16 + lhi * 4 + r] = asum[r];
          redSp[wid * 128 + m * 16 + lhi * 4 + r] = psum[r];
        }
      }
      // acc[m][*] consumed; zero for next tile
#pragma unroll
      for (int j = 0; j < 4; ++j) acc[m][j] = (f32x4){0.f, 0.f, 0.f, 0.f};
    }
    EBAR;
    if (t < 256) {
      const int wrg = t >> 7;
      float a = 0.f, p = 0.f;
#pragma unroll
      for (int w = 0; w < 4; ++w) {
        a += redSa[(wrg * 4 + w) * 128 + (t & 127)];
        p += redSp[(wrg * 4 + w) * 128 + (t & 127)];
      }
      part_all[(size_t)cg * N + rowbase + t] = a;
      part_pos[(size_t)cg * N + rowbase + t] = p;
    }
    // WAR on redS vs next tile's epilogue is separated by 16 s_barriers.
  }
}

// Stage 1: one row per thread, coalesced over cs; per-block tree reduce.
__global__ __launch_bounds__(256) void row_reduce(
    const float* __restrict__ part_pos, const float* __restrict__ part_all,
    float* __restrict__ blocksum) {
  const int i = blockIdx.x * 256 + threadIdx.x;
  float a = 0.f, p = 0.f;
#pragma unroll 4
  for (int cs = 0; cs < CGROUPS; ++cs) {
    a += part_all[(size_t)cs * N + i];
    p += part_pos[(size_t)cs * N + i];
  }
  float s = logf(a) - logf(p);
  __shared__ float red[256];
  red[threadIdx.x] = s;
  __syncthreads();
  for (int off = 128; off > 0; off >>= 1) {
    if (threadIdx.x < off) red[threadIdx.x] += red[threadIdx.x + off];
    __syncthreads();
  }
  if (threadIdx.x == 0) blocksum[blockIdx.x] = red[0];
}

__global__ __launch_bounds__(64) void final_sum(
    const float* __restrict__ blocksum, float* __restrict__ out) {
  float s = (threadIdx.x < N / 256) ? blocksum[threadIdx.x] : 0.f;
#pragma unroll
  for (int m = 1; m <= 32; m <<= 1) s += __shfl_xor(s, m);
  if (threadIdx.x == 0) out[0] = s / (float)N;
}

extern "C" void kernel_launch(void* const* d_in, const int* in_sizes, int n_in,
                              void* d_out, int out_size, void* d_ws, size_t ws_size,
                              hipStream_t stream) {
  const float* out0   = (const float*)d_in[0];
  const float* out1   = (const float*)d_in[1];
  const int*   labels = (const int*)d_in[2];
  float*       out    = (float*)d_out;

  char* ws = (char*)d_ws;
  unsigned short* n0 = (unsigned short*)ws;                          // 8 MB
  unsigned short* n1 = (unsigned short*)(ws + (size_t)N * D * 2);    // 8 MB
  float* part_pos = (float*)(ws + (size_t)2 * N * D * 2);            // 1 MB
  float* part_all = part_pos + (size_t)CGROUPS * N;                  // 1 MB
  float* blocksum = part_all + (size_t)CGROUPS * N;                  // 128 B

  hipLaunchKernelGGL(normalize_kernel, dim3(2 * N / 4), dim3(256), 0, stream,
                     out0, out1, n0, n1);
  hipLaunchKernelGGL(ntxent_main, dim3(256), dim3(512), 0, stream,
                     n0, n1, labels, part_pos, part_all);
  hipLaunchKernelGGL(row_reduce, dim3(N / 256), dim3(256), 0, stream,
                     part_pos, part_all, blocksum);
  hipLaunchKernelGGL(final_sum, dim3(1), dim3(64), 0, stream,
                     blocksum, out);
}

// Round 11
// 148.842 us; speedup vs baseline: 1.0664x; 1.0664x over previous
//
#include <hip/hip_runtime.h>

using short8  = __attribute__((ext_vector_type(8))) short;
using ushort8 = __attribute__((ext_vector_type(8))) unsigned short;
using f32x4   = __attribute__((ext_vector_type(4))) float;

constexpr int   N = 8192;
constexpr int   D = 512;
// sqrt((1/T) * log2(e)) folded into the normalized vectors; dot then feeds exp2 directly.
constexpr float SCALE_FOLD = 1.6986436f;
constexpr int   CGROUPS = 32;                        // 32 col groups of 256

static __device__ __forceinline__ unsigned short f2bf(float x) {
  unsigned u = __float_as_uint(x);
  unsigned r = (u + 0x7fffu + ((u >> 16) & 1u)) >> 16;   // RNE
  return (unsigned short)r;
}

static __device__ __forceinline__ void gld16(const unsigned short* g, unsigned short* l) {
  __builtin_amdgcn_global_load_lds(
      (const __attribute__((address_space(1))) void*)g,
      (__attribute__((address_space(3))) void*)l, 16, 0, 0);
}

// One wave per row; rows [0,N) -> out0, [N,2N) -> out1.
__global__ __launch_bounds__(256) void normalize_kernel(
    const float* __restrict__ in0, const float* __restrict__ in1,
    unsigned short* __restrict__ n0, unsigned short* __restrict__ n1) {
  int gw   = (blockIdx.x * 256 + threadIdx.x) >> 6;
  int lane = threadIdx.x & 63;
  const float* src = (gw < N) ? in0 + (size_t)gw * D : in1 + (size_t)(gw - N) * D;
  unsigned short* dst = (gw < N) ? n0 + (size_t)gw * D : n1 + (size_t)(gw - N) * D;

  const float4* s4 = reinterpret_cast<const float4*>(src) + (size_t)lane * 2;
  float4 v0 = s4[0], v1 = s4[1];
  float ss = v0.x*v0.x + v0.y*v0.y + v0.z*v0.z + v0.w*v0.w
           + v1.x*v1.x + v1.y*v1.y + v1.z*v1.z + v1.w*v1.w;
#pragma unroll
  for (int m = 1; m <= 32; m <<= 1) ss += __shfl_xor(ss, m);
  float scale = SCALE_FOLD / fmaxf(sqrtf(ss), 1e-12f);

  ushort8 o;
  o[0] = f2bf(v0.x * scale); o[1] = f2bf(v0.y * scale);
  o[2] = f2bf(v0.z * scale); o[3] = f2bf(v0.w * scale);
  o[4] = f2bf(v1.x * scale); o[5] = f2bf(v1.y * scale);
  o[6] = f2bf(v1.z * scale); o[7] = f2bf(v1.w * scale);
  *(reinterpret_cast<ushort8*>(dst) + lane) = o;
}

// Persistent fused GEMM: 256 blocks (1/CU), each block = 1 rowtile x 4 colgroups,
// ONE continuous 64-K-tile pipeline (4-deep circular LDS, counted vmcnt gates).
// Epilogue per-m folded; row labels live in LDS (not VGPRs) to stay spill-free.
__global__ __launch_bounds__(512, 2) void ntxent_main(
    const unsigned short* __restrict__ n0, const unsigned short* __restrict__ n1,
    const int* __restrict__ labels,
    float* __restrict__ part_pos, float* __restrict__ part_all) {
  __shared__ unsigned short As[4][256 * 32];   // 64 KiB
  __shared__ unsigned short Bs[4][256 * 32];   // 64 KiB
  __shared__ float redS[2048];                 // 8 KiB: [8][128] all + [8][128] pos
  __shared__ int   labL[256];                  // 1 KiB: row labels for this rowtile

  const int t    = threadIdx.x;
  const int lane = t & 63;
  const int wid  = t >> 6;
  const int lr   = lane & 15;
  const int lhi  = lane >> 4;
  const int wr   = wid >> 2;   // 0/1 : rows wr*128..+128
  const int wc   = wid & 3;    // 0..3: cols wc*64..+64

  const int xcd     = blockIdx.x & 7;    // natural XCD assignment (bid % 8)
  const int rowtile = blockIdx.x >> 3;   // 0..31
  const int rowbase = rowtile * 256;

  if (t < 256) labL[t] = labels[rowbase + t];   // visible after first gate

  // ---- staging addresses (pre-swizzled global source; linear gld16 dest) ----
  const int gslot = (t & 3) ^ ((t >> 3) & 3);
  const unsigned short* gA = n0 + (size_t)(rowbase + (t >> 2)) * D + gslot * 8;

  // ---- ds_read indices (swizzled; measured 0-conflict) ----
  const int ksl = lhi ^ ((lr >> 1) & 3);
  int aidx[8];
#pragma unroll
  for (int m = 0; m < 8; ++m) aidx[m] = (wr * 128 + m * 16 + lr) * 32 + ksl * 8;
  int bidx[4];
#pragma unroll
  for (int j = 0; j < 4; ++j) bidx[j] = (wc * 64 + j * 16 + lr) * 32 + ksl * 8;

#define GATE8 asm volatile("s_waitcnt vmcnt(8)\n\ts_barrier" ::: "memory")
#define GATE4 asm volatile("s_waitcnt vmcnt(4)\n\ts_barrier" ::: "memory")
#define GATE0 asm volatile("s_waitcnt vmcnt(0)\n\ts_barrier" ::: "memory")
#define EBAR  asm volatile("s_waitcnt lgkmcnt(0)\n\ts_barrier" ::: "memory")

  f32x4 acc[8][4];
#pragma unroll
  for (int m = 0; m < 8; ++m)
#pragma unroll
    for (int j = 0; j < 4; ++j) acc[m][j] = (f32x4){0.f, 0.f, 0.f, 0.f};

  // prologue: stage global k-tiles 0,1,2 (tile tt=0)
  {
    const unsigned short* gB0 =
        n1 + (size_t)((xcd * 4) * 256 + (t >> 2)) * D + gslot * 8;
#pragma unroll
    for (int pt = 0; pt < 3; ++pt) {
      const unsigned short* ga = gA + pt * 32;
      const unsigned short* gb = gB0 + pt * 32;
      unsigned short* la = &As[pt][0] + wid * 512;
      unsigned short* lb = &Bs[pt][0] + wid * 512;
      gld16(ga, la); gld16(ga + (size_t)128 * D, la + 4096);
      gld16(gb, lb); gld16(gb + (size_t)128 * D, lb + 4096);
    }
  }

  for (int tt = 0; tt < 4; ++tt) {
    const int cg   = xcd * 4 + tt;
    const int colb = cg * 256;
    const unsigned short* gBc = n1 + (size_t)(colb + (t >> 2)) * D + gslot * 8;
    const unsigned short* gBn = gBc + (size_t)256 * D;   // next tile (unused at tt=3)
    const bool last = (tt == 3);

#pragma unroll
    for (int kk = 0; kk < 16; ++kk) {
      // gate: drain own oldest k-tile's 4 loads, keep 8 in flight
      if (last && kk == 15)      { GATE0; }
      else if (last && kk == 14) { GATE4; }
      else                       { GATE8; }

      // stage global k-tile kk+3 into buf (kk+3)&3 (readers finished, see gate)
      if (!(last && kk >= 13)) {
        const int sb = (kk + 3) & 3;
        const unsigned short* ga = gA + ((kk + 3) & 15) * 32;
        const unsigned short* gb =
            (kk < 13) ? (gBc + (kk + 3) * 32) : (gBn + (kk - 13) * 32);
        unsigned short* la = &As[sb][0] + wid * 512;
        unsigned short* lb = &Bs[sb][0] + wid * 512;
        gld16(ga, la); gld16(ga + (size_t)128 * D, la + 4096);
        gld16(gb, lb); gld16(gb + (size_t)128 * D, lb + 4096);
      }

      // compute on buf kk&3
      const unsigned short* bufA = &As[kk & 3][0];
      const unsigned short* bufB = &Bs[kk & 3][0];
      short8 a[8], b[4];
#pragma unroll
      for (int m = 0; m < 8; ++m) a[m] = *(const short8*)&bufA[aidx[m]];
#pragma unroll
      for (int j = 0; j < 4; ++j) b[j] = *(const short8*)&bufB[bidx[j]];

      __builtin_amdgcn_s_setprio(1);
#pragma unroll
      for (int m = 0; m < 8; ++m)
#pragma unroll
        for (int j = 0; j < 4; ++j)
          acc[m][j] = __builtin_amdgcn_mfma_f32_16x16x32_bf16(a[m], b[j], acc[m][j], 0, 0, 0);
      __builtin_amdgcn_s_setprio(0);
    }

    // ---- per-tile epilogue, per-m folded (row labels read from LDS) ----
    int labc[4];
#pragma unroll
    for (int j = 0; j < 4; ++j) labc[j] = labels[colb + wc * 64 + j * 16 + lr];

    float* redSa = redS;            // [8][128]
    float* redSp = redS + 1024;     // [8][128]
#pragma unroll
    for (int m = 0; m < 8; ++m) {
      const int4 lab4 = *(const int4*)&labL[wr * 128 + m * 16 + lhi * 4];
      float asum[4] = {0.f, 0.f, 0.f, 0.f};
      float psum[4] = {0.f, 0.f, 0.f, 0.f};
#pragma unroll
      for (int j = 0; j < 4; ++j) {
        float e0 = exp2f(acc[m][j][0]);
        float e1 = exp2f(acc[m][j][1]);
        float e2 = exp2f(acc[m][j][2]);
        float e3 = exp2f(acc[m][j][3]);
        asum[0] += e0; asum[1] += e1; asum[2] += e2; asum[3] += e3;
        if (lab4.x == labc[j]) psum[0] += e0;
        if (lab4.y == labc[j]) psum[1] += e1;
        if (lab4.z == labc[j]) psum[2] += e2;
        if (lab4.w == labc[j]) psum[3] += e3;
      }
#pragma unroll
      for (int msk = 1; msk <= 8; msk <<= 1)
#pragma unroll
        for (int r = 0; r < 4; ++r) {
          asum[r] += __shfl_xor(asum[r], msk);
          psum[r] += __shfl_xor(psum[r], msk);
        }
      if (lr == 0) {
#pragma unroll
        for (int r = 0; r < 4; ++r) {
          redSa[wid * 128 + m * 16 + lhi * 4 + r] = asum[r];
          redSp[wid * 128 + m * 16 + lhi * 4 + r] = psum[r];
        }
      }
      // acc[m][*] consumed; zero for next tile
#pragma unroll
      for (int j = 0; j < 4; ++j) acc[m][j] = (f32x4){0.f, 0.f, 0.f, 0.f};
    }
    EBAR;
    if (t < 256) {
      const int wrg = t >> 7;
      float a = 0.f, p = 0.f;
#pragma unroll
      for (int w = 0; w < 4; ++w) {
        a += redSa[(wrg * 4 + w) * 128 + (t & 127)];
        p += redSp[(wrg * 4 + w) * 128 + (t & 127)];
      }
      part_all[(size_t)cg * N + rowbase + t] = a;
      part_pos[(size_t)cg * N + rowbase + t] = p;
    }
    // WAR on redS vs next tile's epilogue is separated by 16 gates.
  }
}

// Stage 1: one row per thread, coalesced over cs; per-block tree reduce.
__global__ __launch_bounds__(256) void row_reduce(
    const float* __restrict__ part_pos, const float* __restrict__ part_all,
    float* __restrict__ blocksum) {
  const int i = blockIdx.x * 256 + threadIdx.x;
  float a = 0.f, p = 0.f;
#pragma unroll 4
  for (int cs = 0; cs < CGROUPS; ++cs) {
    a += part_all[(size_t)cs * N + i];
    p += part_pos[(size_t)cs * N + i];
  }
  float s = logf(a) - logf(p);
  __shared__ float red[256];
  red[threadIdx.x] = s;
  __syncthreads();
  for (int off = 128; off > 0; off >>= 1) {
    if (threadIdx.x < off) red[threadIdx.x] += red[threadIdx.x + off];
    __syncthreads();
  }
  if (threadIdx.x == 0) blocksum[blockIdx.x] = red[0];
}

__global__ __launch_bounds__(64) void final_sum(
    const float* __restrict__ blocksum, float* __restrict__ out) {
  float s = (threadIdx.x < N / 256) ? blocksum[threadIdx.x] : 0.f;
#pragma unroll
  for (int m = 1; m <= 32; m <<= 1) s += __shfl_xor(s, m);
  if (threadIdx.x == 0) out[0] = s / (float)N;
}

extern "C" void kernel_launch(void* const* d_in, const int* in_sizes, int n_in,
                              void* d_out, int out_size, void* d_ws, size_t ws_size,
                              hipStream_t stream) {
  const float* out0   = (const float*)d_in[0];
  const float* out1   = (const float*)d_in[1];
  const int*   labels = (const int*)d_in[2];
  float*       out    = (float*)d_out;

  char* ws = (char*)d_ws;
  unsigned short* n0 = (unsigned short*)ws;                          // 8 MB
  unsigned short* n1 = (unsigned short*)(ws + (size_t)N * D * 2);    // 8 MB
  float* part_pos = (float*)(ws + (size_t)2 * N * D * 2);            // 1 MB
  float* part_all = part_pos + (size_t)CGROUPS * N;                  // 1 MB
  float* blocksum = part_all + (size_t)CGROUPS * N;                  // 128 B

  hipLaunchKernelGGL(normalize_kernel, dim3(2 * N / 4), dim3(256), 0, stream,
                     out0, out1, n0, n1);
  hipLaunchKernelGGL(ntxent_main, dim3(256), dim3(512), 0, stream,
                     n0, n1, labels, part_pos, part_all);
  hipLaunchKernelGGL(row_reduce, dim3(N / 256), dim3(256), 0, stream,
                     part_pos, part_all, blocksum);
  hipLaunchKernelGGL(final_sum, dim3(1), dim3(64), 0, stream,
                     blocksum, out);
}

// Round 12
// 139.832 us; speedup vs baseline: 1.1352x; 1.0644x over previous
//
#include <hip/hip_runtime.h>

using short8  = __attribute__((ext_vector_type(8))) short;
using ushort8 = __attribute__((ext_vector_type(8))) unsigned short;
using f32x4   = __attribute__((ext_vector_type(4))) float;

constexpr int   N = 8192;
constexpr int   D = 512;
// sqrt((1/T) * log2(e)) folded into the normalized vectors; dot feeds exp2 directly.
constexpr float SCALE_FOLD = 1.6986436f;
constexpr int   CGROUPS = 64;                        // 64 col groups of 128

static __device__ __forceinline__ unsigned short f2bf(float x) {
  unsigned u = __float_as_uint(x);
  unsigned r = (u + 0x7fffu + ((u >> 16) & 1u)) >> 16;   // RNE
  return (unsigned short)r;
}

static __device__ __forceinline__ void gld16(const unsigned short* g, unsigned short* l) {
  __builtin_amdgcn_global_load_lds(
      (const __attribute__((address_space(1))) void*)g,
      (__attribute__((address_space(3))) void*)l, 16, 0, 0);
}

// One wave per row; rows [0,N) -> out0, [N,2N) -> out1.
__global__ __launch_bounds__(256) void normalize_kernel(
    const float* __restrict__ in0, const float* __restrict__ in1,
    unsigned short* __restrict__ n0, unsigned short* __restrict__ n1) {
  int gw   = (blockIdx.x * 256 + threadIdx.x) >> 6;
  int lane = threadIdx.x & 63;
  const float* src = (gw < N) ? in0 + (size_t)gw * D : in1 + (size_t)(gw - N) * D;
  unsigned short* dst = (gw < N) ? n0 + (size_t)gw * D : n1 + (size_t)(gw - N) * D;

  const float4* s4 = reinterpret_cast<const float4*>(src) + (size_t)lane * 2;
  float4 v0 = s4[0], v1 = s4[1];
  float ss = v0.x*v0.x + v0.y*v0.y + v0.z*v0.z + v0.w*v0.w
           + v1.x*v1.x + v1.y*v1.y + v1.z*v1.z + v1.w*v1.w;
#pragma unroll
  for (int m = 1; m <= 32; m <<= 1) ss += __shfl_xor(ss, m);
  float scale = SCALE_FOLD / fmaxf(sqrtf(ss), 1e-12f);

  ushort8 o;
  o[0] = f2bf(v0.x * scale); o[1] = f2bf(v0.y * scale);
  o[2] = f2bf(v0.z * scale); o[3] = f2bf(v0.w * scale);
  o[4] = f2bf(v1.x * scale); o[5] = f2bf(v1.y * scale);
  o[6] = f2bf(v1.z * scale); o[7] = f2bf(v1.w * scale);
  *(reinterpret_cast<ushort8*>(dst) + lane) = o;
}

// m97-style fused GEMM: 128x128 tile per block, 4 waves, K=512 (16 steps),
// 3-deep circular LDS (48 KiB) with counted vmcnt(4) gates, 0-conflict swizzle.
// >=3 blocks/CU resident -> cross-block overlap hides fills and barriers.
__global__ __launch_bounds__(256) void ntxent_main(
    const unsigned short* __restrict__ n0, const unsigned short* __restrict__ n1,
    const int* __restrict__ labels,
    float* __restrict__ part_pos, float* __restrict__ part_all) {
  __shared__ unsigned short As[3][128 * 32];   // 24 KiB
  __shared__ unsigned short Bs[3][128 * 32];   // 24 KiB
  __shared__ float redS[256];                  // 1 KiB cross-wave scratch
  __shared__ int   labL[128];                  // 0.5 KiB row labels

  const int t    = threadIdx.x;
  const int lane = t & 63;
  const int wid  = t >> 6;
  const int lr   = lane & 15;
  const int lhi  = lane >> 4;
  const int wr   = wid >> 1;   // 0/1 : rows wr*64..+64
  const int wc   = wid & 1;    // 0/1 : cols wc*64..+64

  // Bijective XCD swizzle (grid = 4096, %8==0)
  const int swz = (blockIdx.x & 7) * 512 + (blockIdx.x >> 3);
  const int rowtile = swz >> 6;        // 0..63
  const int colgrp  = swz & 63;        // 0..63
  const int rowbase = rowtile * 128;
  const int colb    = colgrp * 128;

  if (t < 128) labL[t] = labels[rowbase + t];

  // ---- staging (pre-swizzled global source; linear gld16 dest) ----
  // K-tile = [128 rows][4 slots x 16B]; phys slot = slot ^ ((row>>1)&3).
  // Sweep s: 256 thr x 16B = 64 rows; thread t -> row s*64+(t>>2), phys slot t&3.
  const int gslot = (t & 3) ^ ((t >> 3) & 3);
  const unsigned short* gA = n0 + (size_t)(rowbase + (t >> 2)) * D + gslot * 8;
  const unsigned short* gB = n1 + (size_t)(colb    + (t >> 2)) * D + gslot * 8;
  unsigned short* const lA = &As[0][0] + wid * 512;   // wave-uniform base
  unsigned short* const lB = &Bs[0][0] + wid * 512;

#define STAGE(st, sb) do { \
    const unsigned short* _ga = gA + (st) * 32; \
    const unsigned short* _gb = gB + (st) * 32; \
    unsigned short* _la = lA + (sb) * 4096; \
    unsigned short* _lb = lB + (sb) * 4096; \
    gld16(_ga, _la); gld16(_ga + (size_t)64 * D, _la + 2048); \
    gld16(_gb, _lb); gld16(_gb + (size_t)64 * D, _lb + 2048); \
  } while (0)

  // ---- ds_read indices (swizzled; measured 0-conflict) ----
  const int ksl = lhi ^ ((lr >> 1) & 3);
  int aidx[4];
#pragma unroll
  for (int m = 0; m < 4; ++m) aidx[m] = (wr * 64 + m * 16 + lr) * 32 + ksl * 8;
  int bidx[4];
#pragma unroll
  for (int j = 0; j < 4; ++j) bidx[j] = (wc * 64 + j * 16 + lr) * 32 + ksl * 8;

#define GATE4 asm volatile("s_waitcnt vmcnt(4)\n\ts_barrier" ::: "memory")
#define GATE0 asm volatile("s_waitcnt vmcnt(0)\n\ts_barrier" ::: "memory")
#define EBAR  asm volatile("s_waitcnt lgkmcnt(0)\n\ts_barrier" ::: "memory")

  f32x4 acc[4][4];
#pragma unroll
  for (int m = 0; m < 4; ++m)
#pragma unroll
    for (int j = 0; j < 4; ++j) acc[m][j] = (f32x4){0.f, 0.f, 0.f, 0.f};

  // prologue: stage k-tiles 0,1 into bufs 0,1
  STAGE(0, 0);
  STAGE(1, 1);

#pragma unroll
  for (int kk = 0; kk < 16; ++kk) {
    // gate: drain own oldest k-tile's 4 loads; keep 1 tile in flight
    if (kk < 15) { GATE4; } else { GATE0; }

    // stage k-tile kk+2 into buf (kk+2)%3 (its readers finished at step kk-1)
    if (kk < 14) STAGE(kk + 2, (kk + 2) % 3);

    const unsigned short* bufA = &As[kk % 3][0];
    const unsigned short* bufB = &Bs[kk % 3][0];
    short8 a[4], b[4];
#pragma unroll
    for (int m = 0; m < 4; ++m) a[m] = *(const short8*)&bufA[aidx[m]];
#pragma unroll
    for (int j = 0; j < 4; ++j) b[j] = *(const short8*)&bufB[bidx[j]];

    __builtin_amdgcn_s_setprio(1);
#pragma unroll
    for (int m = 0; m < 4; ++m)
#pragma unroll
      for (int j = 0; j < 4; ++j)
        acc[m][j] = __builtin_amdgcn_mfma_f32_16x16x32_bf16(a[m], b[j], acc[m][j], 0, 0, 0);
    __builtin_amdgcn_s_setprio(0);
  }

  // ---- epilogue: e = exp2(dot); masked accumulate; per-m folded ----
  int labc[4];
#pragma unroll
  for (int j = 0; j < 4; ++j) labc[j] = labels[colb + wc * 64 + j * 16 + lr];

  float* redSa = redS;          // [2][64]
  float* redSp = redS + 128;    // [2][64]
#pragma unroll
  for (int m = 0; m < 4; ++m) {
    const int4 lab4 = *(const int4*)&labL[wr * 64 + m * 16 + lhi * 4];
    float asum[4] = {0.f, 0.f, 0.f, 0.f};
    float psum[4] = {0.f, 0.f, 0.f, 0.f};
#pragma unroll
    for (int j = 0; j < 4; ++j) {
      float e0 = exp2f(acc[m][j][0]);
      float e1 = exp2f(acc[m][j][1]);
      float e2 = exp2f(acc[m][j][2]);
      float e3 = exp2f(acc[m][j][3]);
      asum[0] += e0; asum[1] += e1; asum[2] += e2; asum[3] += e3;
      if (lab4.x == labc[j]) psum[0] += e0;
      if (lab4.y == labc[j]) psum[1] += e1;
      if (lab4.z == labc[j]) psum[2] += e2;
      if (lab4.w == labc[j]) psum[3] += e3;
    }
#pragma unroll
    for (int msk = 1; msk <= 8; msk <<= 1)
#pragma unroll
      for (int r = 0; r < 4; ++r) {
        asum[r] += __shfl_xor(asum[r], msk);
        psum[r] += __shfl_xor(psum[r], msk);
      }
    if (wc == 1 && lr == 0) {
#pragma unroll
      for (int r = 0; r < 4; ++r) {
        redSa[wr * 64 + m * 16 + lhi * 4 + r] = asum[r];
        redSp[wr * 64 + m * 16 + lhi * 4 + r] = psum[r];
      }
    }
    // stash own partials in acc slot to re-read after barrier (wc==0 path keeps regs)
    if (wc == 0) {
#pragma unroll
      for (int r = 0; r < 4; ++r) { acc[m][0][r] = asum[r]; acc[m][1][r] = psum[r]; }
    }
  }
  EBAR;
  if (wc == 0 && lr == 0) {
#pragma unroll
    for (int m = 0; m < 4; ++m)
#pragma unroll
      for (int r = 0; r < 4; ++r) {
        int idx = m * 16 + lhi * 4 + r;
        float a = acc[m][0][r] + redSa[wr * 64 + idx];
        float p = acc[m][1][r] + redSp[wr * 64 + idx];
        int row = rowbase + wr * 64 + idx;
        part_all[(size_t)colgrp * N + row] = a;
        part_pos[(size_t)colgrp * N + row] = p;
      }
  }
}

// Stage 1: one row per thread, coalesced over cs; per-block tree reduce.
__global__ __launch_bounds__(256) void row_reduce(
    const float* __restrict__ part_pos, const float* __restrict__ part_all,
    float* __restrict__ blocksum) {
  const int i = blockIdx.x * 256 + threadIdx.x;
  float a = 0.f, p = 0.f;
#pragma unroll 4
  for (int cs = 0; cs < CGROUPS; ++cs) {
    a += part_all[(size_t)cs * N + i];
    p += part_pos[(size_t)cs * N + i];
  }
  float s = logf(a) - logf(p);
  __shared__ float red[256];
  red[threadIdx.x] = s;
  __syncthreads();
  for (int off = 128; off > 0; off >>= 1) {
    if (threadIdx.x < off) red[threadIdx.x] += red[threadIdx.x + off];
    __syncthreads();
  }
  if (threadIdx.x == 0) blocksum[blockIdx.x] = red[0];
}

__global__ __launch_bounds__(64) void final_sum(
    const float* __restrict__ blocksum, float* __restrict__ out) {
  float s = (threadIdx.x < N / 256) ? blocksum[threadIdx.x] : 0.f;
#pragma unroll
  for (int m = 1; m <= 32; m <<= 1) s += __shfl_xor(s, m);
  if (threadIdx.x == 0) out[0] = s / (float)N;
}

extern "C" void kernel_launch(void* const* d_in, const int* in_sizes, int n_in,
                              void* d_out, int out_size, void* d_ws, size_t ws_size,
                              hipStream_t stream) {
  const float* out0   = (const float*)d_in[0];
  const float* out1   = (const float*)d_in[1];
  const int*   labels = (const int*)d_in[2];
  float*       out    = (float*)d_out;

  char* ws = (char*)d_ws;
  unsigned short* n0 = (unsigned short*)ws;                          // 8 MB
  unsigned short* n1 = (unsigned short*)(ws + (size_t)N * D * 2);    // 8 MB
  float* part_pos = (float*)(ws + (size_t)2 * N * D * 2);            // 2 MB
  float* part_all = part_pos + (size_t)CGROUPS * N;                  // 2 MB
  float* blocksum = part_all + (size_t)CGROUPS * N;                  // 128 B

  hipLaunchKernelGGL(normalize_kernel, dim3(2 * N / 4), dim3(256), 0, stream,
                     out0, out1, n0, n1);
  hipLaunchKernelGGL(ntxent_main, dim3(4096), dim3(256), 0, stream,
                     n0, n1, labels, part_pos, part_all);
  hipLaunchKernelGGL(row_reduce, dim3(N / 256), dim3(256), 0, stream,
                     part_pos, part_all, blocksum);
  hipLaunchKernelGGL(final_sum, dim3(1), dim3(64), 0, stream,
                     blocksum, out);
}